// Round 11
// baseline (180.190 us; speedup 1.0000x reference)
//
#include <hip/hip_runtime.h>
#include <hip/hip_bf16.h>

// SNNDecode: z = x @ W^T  (einsum 'bsh,oh->sbo'), then linear LI scan over seq.
//   v_t = v_{t-1} + a*(i_{t-1} - v_{t-1});  i_t = (1-b)*i_{t-1} + z_t;  out[t]=v_t
// d_out = [voltages (2048*64*128)] ++ [v_f (8192)] ++ [i_f (8192)]  (fp32)
//
// Round 11: round-10 structure, but the gemm's epilogue z tile is bf16 in LDS
// (32 KB, exact alias of the 32 KB A-staging buffer) -> static LDS 64->32 KB,
// __launch_bounds__(256,4) -> 4 blocks/CU (1024 = 256 CU x 4, perfect
// residency), 2x waves/SIMD to hide staging latency + barrier drains.
// z-tile uses a (row>>2)&7 XOR swizzle on col bits 4-6: park writes <=2-way,
// scan/stream reads conflict-free.
// ws: [0,4M) vend|iend [64][8192] | [4M,+128K) bf16 W | [4M+128K,+32M) z bf16.

typedef __attribute__((ext_vector_type(4))) float          f4;
typedef __attribute__((ext_vector_type(8))) short          s8;
typedef __attribute__((ext_vector_type(4))) unsigned       u4;
typedef __attribute__((ext_vector_type(4))) unsigned short su4;

#define SEQ    2048
#define HID    512
#define CHAINS 8192          // batch(64) * out(128)
#define VOLT   16777216      // SEQ * CHAINS
#define NCH    64            // SEQ / 32
#define CHUNK  32

__device__ __forceinline__ float clamp01(float x) { return fminf(fmaxf(x, 0.f), 1.f); }

// packed fp32x2 -> bf16x2 (RNE) as one u32; compiler emits v_cvt_pk_bf16_f32
__device__ __forceinline__ unsigned pkbf(float x, float y) {
  float2 t; t.x = x; t.y = y;
  union { __hip_bfloat162 h; unsigned u; } c;
  c.h = __float22bfloat162_rn(t);
  return c.u;
}

__device__ __forceinline__ unsigned short f2bf(float f) {
  union { float f; unsigned u; } c; c.f = f;
  unsigned u = c.u;
  unsigned r = (u + 0x7fffu + ((u >> 16) & 1u)) >> 16;
  return (unsigned short)r;
}

__device__ __forceinline__ float bf2f(unsigned short s) {
  union { unsigned u; float f; } c; c.u = ((unsigned)s) << 16; return c.f;
}

// A-staging LDS swizzle (ushort-index units): conflict-free for ds_write_b128
// staging and ds_read_b128 fragment reads (round-1-verified).
__device__ __forceinline__ int swz(int row, int k) {
  return (row * 64 + k) ^ ((row & 7) << 3);
}

// z-tile LDS index (ushort units): XOR col bits 4-6 with (row>>2)&7 so the
// park write's 4 rows (stride 4) land on 4 distinct bank groups.
__device__ __forceinline__ int zidx(int row, int col) {
  return row * 128 + (col ^ (((row >> 2) & 7) << 4));
}

// ---------------- Phase 0: W (fp32 [128][512]) -> bf16 in ws ---------------
__global__ __launch_bounds__(256) void k_wconv(const float* __restrict__ W,
                                               unsigned short* __restrict__ Wb) {
  const int i = blockIdx.x * 256 + threadIdx.x;
  const f4 lo = ((const f4*)W)[2 * i];
  const f4 hi = ((const f4*)W)[2 * i + 1];
  su4 v0, v1;
#pragma unroll
  for (int j = 0; j < 4; ++j) { v0[j] = f2bf(lo[j]); v1[j] = f2bf(hi[j]); }
  ((su4*)Wb)[2 * i] = v0;
  ((su4*)Wb)[2 * i + 1] = v1;
}

// ---------------- Phase 1 (+2a): GEMM tile + z store + fused chunk scans ---
// ZB=1: z stored bf16 in zbf.  ZB=0: z stored f32 (bf16-rounded) in Out.
template <int ZB>
__global__ __launch_bounds__(256, 4) void k_gemm(const float* __restrict__ X,
                                                 const unsigned short* __restrict__ Wb,
                                                 float* __restrict__ Out,
                                                 unsigned short* __restrict__ zbf,
                                                 const float* __restrict__ tau_syn,
                                                 const float* __restrict__ tau_mem,
                                                 float* __restrict__ ws) {
  __shared__ __align__(16) char smem[32768];
  short* const AS           = (short*)smem;   // [2][128][64] bf16 A tiles (32 KB)
  unsigned short* const ZSb = (unsigned short*)smem;  // [128][128] bf16 z (alias)

  const int tid = threadIdx.x;
  const int blk = blockIdx.x;
  const int m0  = blk << 7;          // global row = b*2048 + t
  const int bI  = blk >> 4;          // batch index
  const int t0  = (blk & 15) << 7;   // t tile base

  const int rbase = tid >> 3;        // 0..31: staging row group
  const int coff  = (tid & 7) << 3;  // staging k offset (8 elems)

  const int lane = tid & 63;
  const int wid  = tid >> 6;
  const int wmb  = (wid >> 1) << 6;  // wave row base: 0/64
  const int wnb  = (wid & 1) << 6;   // wave col base: 0/64
  const int lr   = lane & 15;
  const int lk   = (lane >> 4) << 3;

  const float* pX[4];
#pragma unroll
  for (int c = 0; c < 4; ++c)
    pX[c] = X + (size_t)(m0 + (c << 5) + rbase) * HID + coff;
  const unsigned short* pB[4];
#pragma unroll
  for (int ni = 0; ni < 4; ++ni)
    pB[ni] = Wb + (size_t)(wnb + (ni << 4) + lr) * HID + lk;

  f4 acc[4][4];
#pragma unroll
  for (int mi = 0; mi < 4; ++mi)
#pragma unroll
    for (int ni = 0; ni < 4; ++ni) acc[mi][ni] = (f4){0.f, 0.f, 0.f, 0.f};

  // A register prefetch: ring of 3 (2 steps ahead); static indices via unroll.
  f4 xa[3][4][2];
#pragma unroll
  for (int c = 0; c < 4; ++c) {
    xa[0][c][0] = *(const f4*)(pX[c]);
    xa[0][c][1] = *(const f4*)(pX[c] + 4);
    xa[1][c][0] = *(const f4*)(pX[c] + 64);
    xa[1][c][1] = *(const f4*)(pX[c] + 68);
  }

#pragma unroll
  for (int ks = 0; ks < 8; ++ks) {
    const int cur = ks % 3;
    short* const Ac = AS + ((ks & 1) << 13);
    // Stage current A tile into LDS (consumes xa[cur] = oldest outstanding
    // loads; deeper prefetch stays in flight through the wait).
#pragma unroll
    for (int c = 0; c < 4; ++c) {
      const int row = (c << 5) + rbase;
      u4 va;
      va[0] = pkbf(xa[cur][c][0][0], xa[cur][c][0][1]);
      va[1] = pkbf(xa[cur][c][0][2], xa[cur][c][0][3]);
      va[2] = pkbf(xa[cur][c][1][0], xa[cur][c][1][1]);
      va[3] = pkbf(xa[cur][c][1][2], xa[cur][c][1][3]);
      *(u4*)&Ac[swz(row, coff)] = va;
    }
    __syncthreads();
    // B fragments for this step (L2-resident W), issued BEFORE the deep xa
    // prefetch so their vmcnt-consume (in-order) doesn't drain the xa loads.
    s8 bg[2][4];
#pragma unroll
    for (int kk = 0; kk < 2; ++kk)
#pragma unroll
      for (int ni = 0; ni < 4; ++ni)
        bg[kk][ni] = *(const s8*)(pB[ni] + (ks << 6) + (kk << 5));
    // Deep prefetch: A tile for step ks+2.
    if (ks < 6) {
      const int k0 = (ks + 2) << 6;
      const int nxt = (ks + 2) % 3;
#pragma unroll
      for (int c = 0; c < 4; ++c) {
        xa[nxt][c][0] = *(const f4*)(pX[c] + k0);
        xa[nxt][c][1] = *(const f4*)(pX[c] + k0 + 4);
      }
    }
#pragma unroll
    for (int kk = 0; kk < 2; ++kk) {
      s8 af[4];
#pragma unroll
      for (int mi = 0; mi < 4; ++mi)
        af[mi] = *(const s8*)&Ac[swz(wmb + (mi << 4) + lr, (kk << 5) + lk)];
#pragma unroll
      for (int mi = 0; mi < 4; ++mi)
#pragma unroll
        for (int ni = 0; ni < 4; ++ni)
          acc[mi][ni] = __builtin_amdgcn_mfma_f32_16x16x32_bf16(af[mi], bg[kk][ni],
                                                                acc[mi][ni], 0, 0, 0);
    }
  }

  // ---- Epilogue: park z tile (bf16) in LDS, aliasing the staging buffer ----
  __syncthreads();   // all waves done reading AS
  const int rr = (lane >> 4) << 2;
#pragma unroll
  for (int mi = 0; mi < 4; ++mi)
#pragma unroll
    for (int ni = 0; ni < 4; ++ni)
#pragma unroll
      for (int r = 0; r < 4; ++r)
        ZSb[zidx(wmb + (mi << 4) + rr + r, wnb + (ni << 4) + lr)] =
            f2bf(acc[mi][ni][r]);
  __syncthreads();

  // (a) stream z tile out (8B/thread/iter from LDS, coalesced global)
#pragma unroll
  for (int i = 0; i < 16; ++i) {
    const int idx  = (i << 8) + tid;
    const int toff = idx >> 5;         // row 0..127
    const int c4   = idx & 31;         // 4-col group
    const int colp = (c4 << 2) ^ (((toff >> 2) & 7) << 4);
    const su4 zb = *(const su4*)&ZSb[toff * 128 + colp];
    if (ZB) {
      *(su4*)(zbf + (size_t)(t0 + toff) * 8192 + (bI << 7) + (c4 << 2)) = zb;
    } else {
      f4 zf; zf[0] = bf2f(zb[0]); zf[1] = bf2f(zb[1]);
      zf[2] = bf2f(zb[2]); zf[3] = bf2f(zb[3]);
      *(f4*)(Out + (size_t)(t0 + toff) * 8192 + (bI << 7) + (c4 << 2)) = zf;
    }
  }
  // (b) fused phase 2a: zero-state scans of the FOUR 32-chunks this block owns
  {
    const float a  = 0.001f * clamp01(tau_mem[0]);
    const float eb = 1.f - 0.001f * clamp01(tau_syn[0]);
    const int col = tid & 127, h = tid >> 7;
    const int chain = (bI << 7) + col;
#pragma unroll
    for (int s = 0; s < 2; ++s) {
      const int r0 = (h << 6) + (s << 5);
      float v = 0.f, ii = 0.f;
#pragma unroll 8
      for (int j = 0; j < CHUNK; ++j) {
        const float z = bf2f(ZSb[zidx(r0 + j, col)]);
        v  = v + a * (ii - v);
        ii = eb * ii + z;
      }
      const int q = ((blk & 15) << 2) + (h << 1) + s;   // chunk 0..63
      ws[q * CHAINS + chain]                 = v;   // vend
      ws[NCH * CHAINS + q * CHAINS + chain]  = ii;  // iend
    }
  }
}

// ---------------- Phase 2 (fused combine + emit): each thread reconstructs
// its chunk in-state from the end-state prefix (independent loads, closed-form
// M^32), scans 32 steps writing v to Out; q==63 writes finals.
template <int ZB>
__global__ __launch_bounds__(256) void k_emit(const float* __restrict__ tau_syn,
                                              const float* __restrict__ tau_mem,
                                              float* __restrict__ Out,
                                              const unsigned short* __restrict__ zbf,
                                              const float* __restrict__ ws) {
  const int tid = threadIdx.x;
  const int cg = (blockIdx.x & 31) * 64 + (tid & 63);  // f4 chain-group 0..2047
  const int q  = (blockIdx.x >> 5) * 4 + (tid >> 6);   // chunk 0..63 (wave-uniform)
  const float a  = 0.001f * clamp01(tau_mem[0]);
  const float bb = 0.001f * clamp01(tau_syn[0]);
  const float ea = 1.f - a, eb = 1.f - bb;
  // M^32 first row [P,Q]; [M^32]_11 = R
  float P = 1.f, Q = 0.f, R = 1.f;
#pragma unroll
  for (int j = 0; j < CHUNK; ++j) { float Pn = P * ea; Q = P * a + Q * eb; P = Pn; R *= eb; }

  const f4* vend = (const f4*)ws;          // [64][2048]
  const f4* iend = vend + NCH * 2048;
  f4 sv = (f4){0.f, 0.f, 0.f, 0.f}, si = (f4){0.f, 0.f, 0.f, 0.f};
#pragma unroll 4
  for (int p = 0; p < q; ++p) {            // independent, pipelineable loads
    const f4 ve = vend[p * 2048 + cg];
    const f4 ie = iend[p * 2048 + cg];
    const f4 nv = P * sv + Q * si + ve;
    si = R * si + ie;
    sv = nv;
  }

  f4* o4 = (f4*)Out;
  const int tb = q << 5;
  f4 v = sv, ii = si;
#pragma unroll 8
  for (int j = 0; j < CHUNK; ++j) {
    const size_t idx = (size_t)(tb + j) * 2048 + cg;
    f4 z;
    if (ZB) {
      const su4 zb = *(const su4*)(zbf + (((size_t)(tb + j)) << 13) + (cg << 2));
      z[0] = bf2f(zb[0]); z[1] = bf2f(zb[1]); z[2] = bf2f(zb[2]); z[3] = bf2f(zb[3]);
    } else {
      z = o4[idx];
    }
    v  = v + a * (ii - v);
    o4[idx] = v;
    ii = eb * ii + z;
  }
  if (q == NCH - 1) {
    ((f4*)(Out + VOLT))[cg]          = v;    // v_f
    ((f4*)(Out + VOLT + CHAINS))[cg] = ii;   // i_f
  }
}

extern "C" void kernel_launch(void* const* d_in, const int* in_sizes, int n_in,
                              void* d_out, int out_size, void* d_ws, size_t ws_size,
                              hipStream_t stream) {
  const float* X   = (const float*)d_in[0];  // [64][2048][512]
  const float* W   = (const float*)d_in[1];  // [128][512]
  const float* tsy = (const float*)d_in[2];
  const float* tme = (const float*)d_in[3];
  float* Out = (float*)d_out;
  float* ws  = (float*)d_ws;
  unsigned short* Wb  = (unsigned short*)((char*)d_ws + (4u << 20));
  unsigned short* zbf = (unsigned short*)((char*)d_ws + (4u << 20) + (128u << 10));
  const size_t need = (4ull << 20) + (128ull << 10) + (32ull << 20);

  k_wconv<<<32, 256, 0, stream>>>(W, Wb);
  if (ws_size >= need) {
    k_gemm<1><<<1024, 256, 0, stream>>>(X, Wb, Out, zbf, tsy, tme, ws);
    k_emit<1><<<512, 256, 0, stream>>>(tsy, tme, Out, zbf, ws);
  } else {
    k_gemm<0><<<1024, 256, 0, stream>>>(X, Wb, Out, zbf, tsy, tme, ws);
    k_emit<0><<<512, 256, 0, stream>>>(tsy, tme, Out, zbf, ws);
  }
}

// Round 12
// 104.999 us; speedup vs baseline: 1.7161x; 1.7161x over previous
//
#include <hip/hip_runtime.h>
#include <hip/hip_bf16.h>

// SNNDecode: z = x @ W^T  (einsum 'bsh,oh->sbo'), then linear LI scan over seq.
//   v_t = v_{t-1} + a*(i_{t-1} - v_{t-1});  i_t = (1-b)*i_{t-1} + z_t;  out[t]=v_t
// d_out = [voltages (2048*64*128)] ++ [v_f (8192)] ++ [i_f (8192)]  (fp32)
//
// Round 12: round-10 champion (104.2 us) + k_comb: chunk in-states computed by
// an in-LDS Hillis-Steele affine scan over the 64 chunk end-states (6 steps),
// written IN PLACE over vend/iend. k_emit loses its per-thread prefix loop
// (~131 MB L2/L3 amplification + 64-deep dep chain) and reads one (v,i) pair.
// Finals (v_f/i_f) move to k_comb. gemm untouched (VGPR cap lesson: round 11's
// launch_bounds(256,4) forced VGPR=64 -> 194 MB scratch spill, 1.7x slower).
// ws: [0,4M) vend|iend [64][8192] | [4M,+128K) bf16 W | [4M+128K,+32M) z bf16.

typedef __attribute__((ext_vector_type(4))) float          f4;
typedef __attribute__((ext_vector_type(8))) short          s8;
typedef __attribute__((ext_vector_type(4))) unsigned       u4;
typedef __attribute__((ext_vector_type(2))) unsigned       u2;
typedef __attribute__((ext_vector_type(4))) unsigned short su4;

#define SEQ    2048
#define HID    512
#define CHAINS 8192          // batch(64) * out(128)
#define VOLT   16777216      // SEQ * CHAINS
#define NCH    64            // SEQ / 32
#define CHUNK  32

__device__ __forceinline__ float clamp01(float x) { return fminf(fmaxf(x, 0.f), 1.f); }

// packed fp32x2 -> bf16x2 (RNE) as one u32; compiler emits v_cvt_pk_bf16_f32
__device__ __forceinline__ unsigned pkbf(float x, float y) {
  float2 t; t.x = x; t.y = y;
  union { __hip_bfloat162 h; unsigned u; } c;
  c.h = __float22bfloat162_rn(t);
  return c.u;
}

__device__ __forceinline__ unsigned short f2bf(float f) {
  union { float f; unsigned u; } c; c.f = f;
  unsigned u = c.u;
  unsigned r = (u + 0x7fffu + ((u >> 16) & 1u)) >> 16;
  return (unsigned short)r;
}

__device__ __forceinline__ float bf2f(unsigned short s) {
  union { unsigned u; float f; } c; c.u = ((unsigned)s) << 16; return c.f;
}

// LDS swizzle (ushort-index units): conflict-free for both ds_write_b128
// staging and ds_read_b128 fragment reads (round-1-verified).
__device__ __forceinline__ int swz(int row, int k) {
  return (row * 64 + k) ^ ((row & 7) << 3);
}

// ---------------- Phase 0: W (fp32 [128][512]) -> bf16 in ws ---------------
__global__ __launch_bounds__(256) void k_wconv(const float* __restrict__ W,
                                               unsigned short* __restrict__ Wb) {
  const int i = blockIdx.x * 256 + threadIdx.x;
  const f4 lo = ((const f4*)W)[2 * i];
  const f4 hi = ((const f4*)W)[2 * i + 1];
  su4 v0, v1;
#pragma unroll
  for (int j = 0; j < 4; ++j) { v0[j] = f2bf(lo[j]); v1[j] = f2bf(hi[j]); }
  ((su4*)Wb)[2 * i] = v0;
  ((su4*)Wb)[2 * i + 1] = v1;
}

// ---------------- Phase 1 (+2a): GEMM tile + z store + fused chunk scans ---
// ZB=1: z stored bf16 in zbf.  ZB=0: z stored f32 in Out (round-6 fallback).
template <int ZB>
__global__ __launch_bounds__(256, 2) void k_gemm(const float* __restrict__ X,
                                                 const unsigned short* __restrict__ Wb,
                                                 float* __restrict__ Out,
                                                 unsigned short* __restrict__ zbf,
                                                 const float* __restrict__ tau_syn,
                                                 const float* __restrict__ tau_mem,
                                                 float* __restrict__ ws) {
  __shared__ __align__(16) char smem[65536];
  short* const AS = (short*)smem;            // [2][128][64] bf16 A tiles (32 KB)
  float* const ZS = (float*)smem;            // [128][128] f32 z tile (aliased)

  const int tid = threadIdx.x;
  const int blk = blockIdx.x;
  const int m0  = blk << 7;          // global row = b*2048 + t
  const int bI  = blk >> 4;          // batch index
  const int t0  = (blk & 15) << 7;   // t tile base

  const int rbase = tid >> 3;        // 0..31: staging row group
  const int coff  = (tid & 7) << 3;  // staging k offset (8 elems)

  const int lane = tid & 63;
  const int wid  = tid >> 6;
  const int wmb  = (wid >> 1) << 6;  // wave row base: 0/64
  const int wnb  = (wid & 1) << 6;   // wave col base: 0/64
  const int lr   = lane & 15;
  const int lk   = (lane >> 4) << 3;

  const float* pX[4];
#pragma unroll
  for (int c = 0; c < 4; ++c)
    pX[c] = X + (size_t)(m0 + (c << 5) + rbase) * HID + coff;
  const unsigned short* pB[4];
#pragma unroll
  for (int ni = 0; ni < 4; ++ni)
    pB[ni] = Wb + (size_t)(wnb + (ni << 4) + lr) * HID + lk;

  f4 acc[4][4];
#pragma unroll
  for (int mi = 0; mi < 4; ++mi)
#pragma unroll
    for (int ni = 0; ni < 4; ++ni) acc[mi][ni] = (f4){0.f, 0.f, 0.f, 0.f};

  // A register prefetch: ring of 3 (2 steps ahead); static indices via unroll.
  f4 xa[3][4][2];
#pragma unroll
  for (int c = 0; c < 4; ++c) {
    xa[0][c][0] = *(const f4*)(pX[c]);
    xa[0][c][1] = *(const f4*)(pX[c] + 4);
    xa[1][c][0] = *(const f4*)(pX[c] + 64);
    xa[1][c][1] = *(const f4*)(pX[c] + 68);
  }

#pragma unroll
  for (int ks = 0; ks < 8; ++ks) {
    const int cur = ks % 3;
    short* const Ac = AS + ((ks & 1) << 13);
    // Stage current A tile into LDS (consumes xa[cur] = oldest outstanding
    // loads; deeper prefetch stays in flight through the wait).
#pragma unroll
    for (int c = 0; c < 4; ++c) {
      const int row = (c << 5) + rbase;
      u4 va;
      va[0] = pkbf(xa[cur][c][0][0], xa[cur][c][0][1]);
      va[1] = pkbf(xa[cur][c][0][2], xa[cur][c][0][3]);
      va[2] = pkbf(xa[cur][c][1][0], xa[cur][c][1][1]);
      va[3] = pkbf(xa[cur][c][1][2], xa[cur][c][1][3]);
      *(u4*)&Ac[swz(row, coff)] = va;
    }
    __syncthreads();
    // B fragments for this step (L2-resident W), issued BEFORE the deep xa
    // prefetch so their vmcnt-consume (in-order) doesn't drain the xa loads.
    s8 bg[2][4];
#pragma unroll
    for (int kk = 0; kk < 2; ++kk)
#pragma unroll
      for (int ni = 0; ni < 4; ++ni)
        bg[kk][ni] = *(const s8*)(pB[ni] + (ks << 6) + (kk << 5));
    // Deep prefetch: A tile for step ks+2.
    if (ks < 6) {
      const int k0 = (ks + 2) << 6;
      const int nxt = (ks + 2) % 3;
#pragma unroll
      for (int c = 0; c < 4; ++c) {
        xa[nxt][c][0] = *(const f4*)(pX[c] + k0);
        xa[nxt][c][1] = *(const f4*)(pX[c] + k0 + 4);
      }
    }
#pragma unroll
    for (int kk = 0; kk < 2; ++kk) {
      s8 af[4];
#pragma unroll
      for (int mi = 0; mi < 4; ++mi)
        af[mi] = *(const s8*)&Ac[swz(wmb + (mi << 4) + lr, (kk << 5) + lk)];
#pragma unroll
      for (int mi = 0; mi < 4; ++mi)
#pragma unroll
        for (int ni = 0; ni < 4; ++ni)
          acc[mi][ni] = __builtin_amdgcn_mfma_f32_16x16x32_bf16(af[mi], bg[kk][ni],
                                                                acc[mi][ni], 0, 0, 0);
    }
  }

  // ---- Epilogue: park z tile in LDS (aliases dead staging buffer) ----
  __syncthreads();   // all waves done reading AS
  const int rr = (lane >> 4) << 2;
#pragma unroll
  for (int mi = 0; mi < 4; ++mi)
#pragma unroll
    for (int ni = 0; ni < 4; ++ni)
#pragma unroll
      for (int r = 0; r < 4; ++r)
        ZS[(wmb + (mi << 4) + rr + r) * 128 + wnb + (ni << 4) + lr] = acc[mi][ni][r];
  __syncthreads();

  // (a) stream z tile out
  if (ZB) {
    unsigned short* const Zrow = zbf + (size_t)t0 * 8192 + (bI << 7);
#pragma unroll
    for (int i = 0; i < 16; ++i) {
      const int idx  = (i << 8) + tid;
      const int toff = idx >> 5;
      const int c4   = idx & 31;
      const f4 zv = *(const f4*)&ZS[toff * 128 + (c4 << 2)];
      u2 pk; pk[0] = pkbf(zv[0], zv[1]); pk[1] = pkbf(zv[2], zv[3]);
      *(u2*)(Zrow + (size_t)toff * 8192 + (c4 << 2)) = pk;
    }
  } else {
    float* const Zrow = Out + (size_t)t0 * 8192 + (bI << 7);
#pragma unroll
    for (int i = 0; i < 16; ++i) {
      const int idx  = (i << 8) + tid;
      const int toff = idx >> 5;
      const int c4   = idx & 31;
      *(f4*)(Zrow + (size_t)toff * 8192 + (c4 << 2)) = *(const f4*)&ZS[toff * 128 + (c4 << 2)];
    }
  }
  // (b) fused phase 2a: zero-state scans of the FOUR 32-chunks this block owns
  {
    const float a  = 0.001f * clamp01(tau_mem[0]);
    const float eb = 1.f - 0.001f * clamp01(tau_syn[0]);
    const int col = tid & 127, h = tid >> 7;
    const int chain = (bI << 7) + col;
#pragma unroll
    for (int s = 0; s < 2; ++s) {
      const int r0 = (h << 6) + (s << 5);
      const float* zs = ZS + r0 * 128 + col;   // bank=col&31: 2-way (free)
      float v = 0.f, ii = 0.f;
#pragma unroll 8
      for (int j = 0; j < CHUNK; ++j) {
        const float z = zs[j * 128];
        v  = v + a * (ii - v);
        ii = eb * ii + z;
      }
      const int q = ((blk & 15) << 2) + (h << 1) + s;   // chunk 0..63
      ws[q * CHAINS + chain]                 = v;   // vend
      ws[NCH * CHAINS + q * CHAINS + chain]  = ii;  // iend
    }
  }
}

// ---------------- Phase 2 (combine): in-LDS Hillis-Steele affine scan over
// the 64 chunk end-states; writes IN-STATES in place over vend/iend; thread
// q==63 (holding inclusive(63) = final state) writes v_f/i_f.
__global__ __launch_bounds__(256) void k_comb(const float* __restrict__ tau_syn,
                                              const float* __restrict__ tau_mem,
                                              float* __restrict__ Out,
                                              float* __restrict__ ws) {
  __shared__ __align__(16) f4 SV[NCH][4], SI[NCH][4];   // 8 KB
  const int tid = threadIdx.x;
  const int q   = tid >> 2;                 // chunk 0..63
  const int s   = tid & 3;
  const int cg  = blockIdx.x * 4 + s;       // f4 chain-group 0..2047
  const float a  = 0.001f * clamp01(tau_mem[0]);
  const float bb = 0.001f * clamp01(tau_syn[0]);
  const float ea = 1.f - a, eb = 1.f - bb;
  // M^32 = [[P,Q],[0,R]] (verified recurrence)
  float P = 1.f, Q = 0.f, R = 1.f;
#pragma unroll
  for (int j = 0; j < CHUNK; ++j) { const float Pn = P * ea; Q = P * a + Q * eb; P = Pn; R *= eb; }

  f4* vend = (f4*)ws;                       // [64][2048]
  f4* iend = vend + NCH * 2048;
  f4 xv = vend[q * 2048 + cg];              // window sum, starts = e(q)
  f4 xi = iend[q * 2048 + cg];
  SV[q][s] = xv; SI[q][s] = xi;

  float Pd = P, Qd = Q, Rd = R;             // M^(32*d), d = 1
#pragma unroll
  for (int d = 1; d < NCH; d <<= 1) {
    __syncthreads();
    f4 av, ai;
    const bool val = (q >= d);
    if (val) { av = SV[q - d][s]; ai = SI[q - d][s]; }
    __syncthreads();
    if (val) {
      xv = xv + Pd * av + Qd * ai;          // x(q) += M^(32d) * x(q-d)
      xi = xi + Rd * ai;
      SV[q][s] = xv; SI[q][s] = xi;
    }
    const float Pn = Pd * Pd;               // M^(64d) = M^(32d) * M^(32d)
    Qd = Pd * Qd + Qd * Rd;
    Pd = Pn;
    Rd = Rd * Rd;
  }
  __syncthreads();
  // in-state(q) = inclusive(q-1); write in place
  f4 iv = (f4){0.f, 0.f, 0.f, 0.f}, ij = (f4){0.f, 0.f, 0.f, 0.f};
  if (q > 0) { iv = SV[q - 1][s]; ij = SI[q - 1][s]; }
  vend[q * 2048 + cg] = iv;
  iend[q * 2048 + cg] = ij;
  if (q == NCH - 1) {                       // inclusive(63) = final state
    ((f4*)(Out + VOLT))[cg]          = xv;  // v_f
    ((f4*)(Out + VOLT + CHAINS))[cg] = xi;  // i_f
  }
}

// ---------------- Phase 3 (emit): read chunk in-state (one pair), scan 32
// steps writing v to Out. Wave-uniform q, coalesced cg (1 KB/wave rows).
template <int ZB>
__global__ __launch_bounds__(256) void k_emit(const float* __restrict__ tau_syn,
                                              const float* __restrict__ tau_mem,
                                              float* __restrict__ Out,
                                              const unsigned short* __restrict__ zbf,
                                              const float* __restrict__ ws) {
  const int tid = threadIdx.x;
  const int cg = (blockIdx.x & 31) * 64 + (tid & 63);  // f4 chain-group 0..2047
  const int q  = (blockIdx.x >> 5) * 4 + (tid >> 6);   // chunk 0..63 (wave-uniform)
  const float a  = 0.001f * clamp01(tau_mem[0]);
  const float eb = 1.f - 0.001f * clamp01(tau_syn[0]);

  const f4* vin = (const f4*)ws;           // [64][2048] (in-states after k_comb)
  const f4* iin = vin + NCH * 2048;
  f4 v  = vin[q * 2048 + cg];
  f4 ii = iin[q * 2048 + cg];

  f4* o4 = (f4*)Out;
  const int tb = q << 5;
#pragma unroll 8
  for (int j = 0; j < CHUNK; ++j) {
    const size_t idx = (size_t)(tb + j) * 2048 + cg;
    f4 z;
    if (ZB) {
      const su4 zb = *(const su4*)(zbf + (((size_t)(tb + j)) << 13) + (cg << 2));
      z[0] = bf2f(zb[0]); z[1] = bf2f(zb[1]); z[2] = bf2f(zb[2]); z[3] = bf2f(zb[3]);
    } else {
      z = o4[idx];
    }
    v  = v + a * (ii - v);
    o4[idx] = v;
    ii = eb * ii + z;
  }
}

extern "C" void kernel_launch(void* const* d_in, const int* in_sizes, int n_in,
                              void* d_out, int out_size, void* d_ws, size_t ws_size,
                              hipStream_t stream) {
  const float* X   = (const float*)d_in[0];  // [64][2048][512]
  const float* W   = (const float*)d_in[1];  // [128][512]
  const float* tsy = (const float*)d_in[2];
  const float* tme = (const float*)d_in[3];
  float* Out = (float*)d_out;
  float* ws  = (float*)d_ws;
  unsigned short* Wb  = (unsigned short*)((char*)d_ws + (4u << 20));
  unsigned short* zbf = (unsigned short*)((char*)d_ws + (4u << 20) + (128u << 10));
  const size_t need = (4ull << 20) + (128ull << 10) + (32ull << 20);

  k_wconv<<<32, 256, 0, stream>>>(W, Wb);
  if (ws_size >= need) {
    k_gemm<1><<<1024, 256, 0, stream>>>(X, Wb, Out, zbf, tsy, tme, ws);
    k_comb<<<512, 256, 0, stream>>>(tsy, tme, Out, ws);
    k_emit<1><<<512, 256, 0, stream>>>(tsy, tme, Out, zbf, ws);
  } else {
    k_gemm<0><<<1024, 256, 0, stream>>>(X, Wb, Out, zbf, tsy, tme, ws);
    k_comb<<<512, 256, 0, stream>>>(tsy, tme, Out, ws);
    k_emit<0><<<512, 256, 0, stream>>>(tsy, tme, Out, zbf, ws);
  }
}